// Round 10
// baseline (56.638 us; speedup 1.0000x reference)
//
#include <hip/hip_runtime.h>
#include <math.h>

#define NB 8
#define PP 4096
#define MM 2048
#define DIRS 2
#define NGRP (DIRS * NB)          // 16 groups, one per (dir,n)
#define QSLICES 16
#define QS (PP / QSLICES)         // 256 q's staged per block
#define TPB 512
#define NPTS 8                    // TPB*NPTS = 4096 = all p per block
#define NLIK (NB * MM)            // 16384
#define NBLK (NGRP * QSLICES)     // 256 blocks = 1 per CU

// d_ws layout: float sums[3]; unsigned tick[17];  (zeroed each launch)
//              pad to 128 B; then float planes[NGRP][QSLICES][PP] (4 MB)

__global__ __launch_bounds__(TPB, 2) void chamfer_fused(
        const float* __restrict__ x, const float* __restrict__ y,
        const float* __restrict__ lik, float* __restrict__ ws,
        float* __restrict__ out) {
    float* sums = ws;
    unsigned* tick = (unsigned*)(ws + 3);
    float* planes = ws + 32;

    const int t = threadIdx.x;
    const int bx = blockIdx.x;
    const int g  = bx >> 4;      // (dir,n) group
    const int qs = bx & 15;
    const int dir = g >> 3;
    const int n   = g & 7;

    const float* a = dir ? y : x;
    const float* b = dir ? x : y;
    const float* an = a + (size_t)n * PP * 3;
    const float* bn = b + (size_t)n * PP * 3;

    __shared__ float4 lds[QS + 4];   // +4: prefetch overrun pad

    // ---- phase A: scan my q-slice against all 4096 p (8 per thread) ----
    float X0[NPTS], X1[NPTS], X2[NPTS], XS[NPTS], M[NPTS];
    #pragma unroll
    for (int i = 0; i < NPTS; ++i) {
        int p = i * TPB + t;
        const float* ap = an + (size_t)p * 3;
        X0[i] = ap[0]; X1[i] = ap[1]; X2[i] = ap[2];
        XS[i] = X0[i]*X0[i] + X1[i]*X1[i] + X2[i]*X2[i];
        M[i] = INFINITY;
    }
    if (t < QS) {   // lds[q] = {-2y0, -2y1, -2y2, |y|^2}
        int q = qs * QS + t;
        const float* bp = bn + (size_t)q * 3;
        float y0 = bp[0], y1 = bp[1], y2 = bp[2];
        lds[t] = make_float4(-2.f*y0, -2.f*y1, -2.f*y2, y0*y0 + y1*y1 + y2*y2);
    } else if (t < QS + 4) {
        lds[t] = make_float4(0.f, 0.f, 0.f, 0.f);
    }
    __syncthreads();

    // 2-deep software pipeline over q-pairs
    float4 A0 = lds[0], B0 = lds[1], A1 = lds[2], B1 = lds[3];
    #pragma unroll 2
    for (int j = 0; j < QS / 2; ++j) {
        float4 A2 = lds[2*j + 4], B2 = lds[2*j + 5];
        #pragma unroll
        for (int i = 0; i < NPTS; ++i) {
            float d0 = fmaf(X0[i], A0.x, fmaf(X1[i], A0.y, fmaf(X2[i], A0.z, A0.w)));
            float d1 = fmaf(X0[i], B0.x, fmaf(X1[i], B0.y, fmaf(X2[i], B0.z, B0.w)));
            M[i] = fminf(fminf(M[i], d0), d1);   // v_min3_f32
        }
        A0 = A1; B0 = B1; A1 = A2; B1 = B2;
    }

    float* myplane = planes + (size_t)(g * QSLICES + qs) * PP;
    #pragma unroll
    for (int i = 0; i < NPTS; ++i)
        myplane[i * TPB + t] = M[i] + XS[i];     // coalesced, no init needed

    // ---- fold log2(lik): 64 elems per block, wave 0 only ----
    if (t < 64) {
        float l = __log2f(lik[bx * 64 + t]);
        #pragma unroll
        for (int off = 32; off; off >>= 1) l += __shfl_down(l, off, 64);
        if (t == 0) atomicAdd(&sums[2], l);
    }

    // ---- group ticket: last of 16 blocks reduces this group's planes ----
    __syncthreads();
    __shared__ int winflag;
    if (t == 0) {
        __threadfence();   // release: drain plane stores device-wide
        winflag = (atomicAdd(&tick[g], 1u) == QSLICES - 1);
    }
    __syncthreads();
    if (!winflag) return;

    __threadfence();       // acquire: invalidate stale cached lines
    const float* gplane = planes + (size_t)g * QSLICES * PP;
    float s = 0.f;
    for (int p = t; p < PP; p += TPB) {
        float m = __hip_atomic_load(&gplane[p], __ATOMIC_RELAXED, __HIP_MEMORY_SCOPE_AGENT);
        #pragma unroll
        for (int sl = 1; sl < QSLICES; ++sl)
            m = fminf(m, __hip_atomic_load(&gplane[sl * PP + p],
                                           __ATOMIC_RELAXED, __HIP_MEMORY_SCOPE_AGENT));
        s += m;
    }
    #pragma unroll
    for (int off = 32; off; off >>= 1) s += __shfl_down(s, off, 64);
    __shared__ float red[8];
    int lane = t & 63, wid = t >> 6;
    if (lane == 0) red[wid] = s;
    __syncthreads();
    __shared__ int finflag;
    if (t == 0) {
        float tot = 0.f;
        #pragma unroll
        for (int w = 0; w < 8; ++w) tot += red[w];
        atomicAdd(&sums[dir], tot);
        __threadfence();
        finflag = (atomicAdd(&tick[16], 1u) == NGRP - 1);
    }
    __syncthreads();
    if (!finflag) return;

    // ---- finalize (last group winner) ----
    if (t == 0) {
        __threadfence();
        float s0 = __hip_atomic_load(&sums[0], __ATOMIC_ACQUIRE, __HIP_MEMORY_SCOPE_AGENT);
        float s1 = __hip_atomic_load(&sums[1], __ATOMIC_ACQUIRE, __HIP_MEMORY_SCOPE_AGENT);
        float s2 = __hip_atomic_load(&sums[2], __ATOMIC_ACQUIRE, __HIP_MEMORY_SCOPE_AGENT);
        float rec = s0 / (float)(NB * PP) + s1 / (float)(NB * PP);
        float bit_y = s2 / (-(float)NB);
        float bpp = bit_y / (float)PP;
        out[0] = bpp + 1.0f * rec;  // loss (LMBDA = 1)
        out[1] = bpp;               // bpp_loss
        out[2] = rec;               // rec_loss
        out[3] = bit_y;             // bit_loss
        out[4] = bpp;               // bpp_y
    }
}

extern "C" void kernel_launch(void* const* d_in, const int* in_sizes, int n_in,
                              void* d_out, int out_size, void* d_ws, size_t ws_size,
                              hipStream_t stream) {
    const float* x_hat  = (const float*)d_in[0];
    const float* points = (const float*)d_in[1];
    const float* lik    = (const float*)d_in[2];
    float* out = (float*)d_out;
    float* ws  = (float*)d_ws;

    hipMemsetAsync(ws, 0, 80, stream);   // sums[3] + tick[17]
    chamfer_fused<<<NBLK, TPB, 0, stream>>>(x_hat, points, lik, ws, out);
}